// Round 10
// baseline (581.000 us; speedup 1.0000x reference)
//
#include <hip/hip_runtime.h>
#include <hip/hip_bf16.h>

#define B_ 16
#define N_ 1024
#define C_ 768
#define H_ 12
#define HD_ 64
#define QC_ (3*C_)      // 2304

using bf16 = __hip_bfloat16;
using bf16x8 = __attribute__((ext_vector_type(8))) __bf16;
using f32x4  = __attribute__((ext_vector_type(4))) float;

__device__ __forceinline__ float tof(bf16 v){ return __bfloat162float(v); }

// Async global->LDS 16B DMA. LDS dest is wave-uniform base + lane*16 (linear);
// swizzle is applied on the per-lane GLOBAL address (rule #21).
__device__ __forceinline__ void gload16(const void* g, void* l) {
  __builtin_amdgcn_global_load_lds(
      (const __attribute__((address_space(1))) unsigned int*)g,
      (__attribute__((address_space(3))) unsigned int*)l, 16, 0, 0);
}

// XCD-aware bijective block swizzle (nwg % 8 == 0 holds for all our grids).
__device__ __forceinline__ int xcd_swizzle(int bid, int nwg) {
  return (bid & 7) * (nwg >> 3) + (bid >> 3);
}

// pack two f32 -> one u32 of 2 bf16
__device__ __forceinline__ unsigned pk2(float a, float b) {
  unsigned ua = (unsigned)__bfloat16_as_ushort(__float2bfloat16(a));
  unsigned ub = (unsigned)__bfloat16_as_ushort(__float2bfloat16(b));
  return ua | (ub << 16);
}

// ---------------------------------------------------------------------------
// Input-dtype detector (1=bf16, 0=fp32) from bits 14:7 of sampled words.
// ---------------------------------------------------------------------------
__global__ __launch_bounds__(256) void detect_dtype(
    const unsigned* __restrict__ x32, int* __restrict__ flag)
{
  __shared__ int cnt;
  if (threadIdx.x == 0) cnt = 0;
  __syncthreads();
  int local = 0;
  #pragma unroll
  for (int i = 0; i < 16; i++) {
    unsigned u = x32[threadIdx.x * 16 + i * 4096];
    unsigned e = (u >> 7) & 0xFF;
    local += (e >= 110 && e <= 140) ? 1 : 0;
  }
  atomicAdd(&cnt, local);
  __syncthreads();
  if (threadIdx.x == 0) *flag = (cnt > 2048) ? 1 : 0;
}

// ---------------------------------------------------------------------------
// Cast x (fp32 or bf16 per flag) -> bf16, 4 elems/thread.
// ---------------------------------------------------------------------------
__global__ __launch_bounds__(256) void cvt_x(
    const void* __restrict__ x, bf16* __restrict__ xb,
    const int* __restrict__ flag, const int n4, const int off4)
{
  const int i = blockIdx.x * 256 + threadIdx.x;
  if (i >= n4) return;
  if (*flag) {
    ((uint2*)xb)[i] = ((const uint2*)x)[off4 + i];
  } else {
    float4 v = ((const float4*)x)[off4 + i];
    xb[i*4+0] = __float2bfloat16(v.x);
    xb[i*4+1] = __float2bfloat16(v.y);
    xb[i*4+2] = __float2bfloat16(v.z);
    xb[i*4+3] = __float2bfloat16(v.w);
  }
}

// ---------------------------------------------------------------------------
// WT[n][k] (bf16) = W[k][n] (dtype per flag). Tiled 32x32 transpose.
// ---------------------------------------------------------------------------
__global__ __launch_bounds__(256) void wt_cvt(
    const void* __restrict__ W, bf16* __restrict__ WT,
    const int K, const int Nd, const int* __restrict__ flag)
{
  __shared__ float t[32][33];
  const int fl = *flag;
  const int n0 = blockIdx.x * 32, k0 = blockIdx.y * 32;
  const int tx = threadIdx.x & 31, ty = threadIdx.x >> 5;   // 32 x 8
  for (int kk = ty; kk < 32; kk += 8) {
    const size_t gi = (size_t)(k0 + kk) * Nd + (n0 + tx);
    t[kk][tx] = fl ? tof(((const bf16*)W)[gi]) : ((const float*)W)[gi];
  }
  __syncthreads();
  for (int nn = ty; nn < 32; nn += 8)
    WT[(size_t)(n0 + nn) * K + (k0 + tx)] = __float2bfloat16(t[tx][nn]);
}

// ---------------------------------------------------------------------------
// Fused qkv GEMM + bias + RoPE + layout scatter. (unchanged, verified)
// Q is scaled by 0.125 * log2(e) so attention S arrives in log2 domain.
// ---------------------------------------------------------------------------
__global__ __launch_bounds__(256) void gemm_qkv_rope(
    const bf16* __restrict__ Ab, const bf16* __restrict__ WT,
    const void* __restrict__ bias, bf16* __restrict__ Qp,
    bf16* __restrict__ Kp, bf16* __restrict__ Vtb,
    const int* __restrict__ flag,
    const int* __restrict__ pos_h, const int* __restrict__ pos_w)
{
  const int K = C_;
  const bool bbf = (*flag != 0);

  __shared__ __align__(16) char smem[36864];
  unsigned short* As = (unsigned short*)smem;
  unsigned short* Bs = (unsigned short*)(smem + 16384);

  const int tid = threadIdx.x;
  const int l   = tid & 63;
  const int w   = tid >> 6;
  const int wm  = (w & 1) * 64;
  const int wn  = (w >> 1) * 64;

  const int nwg = gridDim.x * gridDim.y;
  const int bid = blockIdx.y * gridDim.x + blockIdx.x;
  const int lb  = xcd_swizzle(bid, nwg);
  const int gy  = gridDim.y;                 // 18
  const int brow = lb / gy;
  const int bcol = lb - brow * gy;
  const int row0 = brow * 128;
  const int col0 = bcol * 128;

  const int srow = w*8 + (l >> 3);
  const int sch  = (l & 7) ^ (l >> 3);
  const bf16* Ast = Ab + (size_t)(row0 + srow) * K + sch * 8;
  const bf16* Bst = WT + (size_t)(col0 + srow) * K + sch * 8;

  f32x4 acc[4][4] = {};

  for (int k0 = 0; k0 < K; k0 += 64) {
    __syncthreads();                         // prev iter's LDS reads done
    #pragma unroll
    for (int i = 0; i < 4; i++) {
      gload16(Ast + (size_t)i*32*K + k0, As + (i*32 + w*8)*64);
      gload16(Bst + (size_t)i*32*K + k0, Bs + (i*32 + w*8)*64);
    }
    __syncthreads();                         // drains vmcnt -> LDS ready
    #pragma unroll
    for (int s = 0; s < 2; s++) {
      bf16x8 af[4], bg[4];
      const int ch = (s*4 + (l >> 4)) ^ (l & 7);
      #pragma unroll
      for (int i = 0; i < 4; i++) {
        const int rowm = wm + i*16 + (l & 15);
        const int rown = wn + i*16 + (l & 15);
        af[i] = *(const bf16x8*)&As[rowm*64 + ch*8];
        bg[i] = *(const bf16x8*)&Bs[rown*64 + ch*8];
      }
      #pragma unroll
      for (int i = 0; i < 4; i++)
        #pragma unroll
        for (int j = 0; j < 4; j++)
          acc[i][j] = __builtin_amdgcn_mfma_f32_16x16x32_bf16(
                          af[i], bg[j], acc[i][j], 0, 0, 0);
    }
  }

  // ---- fused epilogue ----
  const int colbase = col0 + wn;            // multiple of 64
  const int t   = colbase / 768;            // 0=q 1=k 2=v (block-uniform)
  const int h   = (colbase % 768) >> 6;     // head (wave-uniform)
  const int dd0 = l & 15;
  float bv4[4];
  #pragma unroll
  for (int j = 0; j < 4; j++) {
    const int c = colbase + dd0 + j*16;
    bv4[j] = bbf ? tof(((const bf16*)bias)[c]) : ((const float*)bias)[c];
  }
  const int rb = row0 + wm + (l >> 4) * 4;

  __syncthreads();                           // As/Bs dead for ALL waves
  bf16* Ts = (bf16*)(smem + w * 9216);       // 64 rows x 72 elems (144 B)

  if (t == 2) {
    #pragma unroll
    for (int i = 0; i < 4; i++) {
      #pragma unroll
      for (int v = 0; v < 4; v++) {
        const int nl = i*16 + ((l >> 4) << 2) + v;   // n_local 0..63
        #pragma unroll
        for (int j = 0; j < 4; j++) {
          const int dl = dd0 + j*16;                 // d_local 0..63
          const float y = acc[i][j][v] + bv4[j];
          Ts[dl*72 + (((nl >> 3) ^ (dl & 7)) << 3) + (nl & 7)] =
              __float2bfloat16(y);
        }
      }
    }
  } else {
    const int fi  = dd0 >> 1;
    const float LOG2B = 13.287712379549449f;  // log2(10000)
    const float f1 = exp2f(-LOG2B * (float)fi       * (1.0f/16.0f));
    const float f2 = exp2f(-LOG2B * (float)(fi + 8) * (1.0f/16.0f));
    #pragma unroll
    for (int i = 0; i < 4; i++) {
      #pragma unroll
      for (int v = 0; v < 4; v++) {
        const int r  = rb + i*16 + v;          // chunk-local row (global)
        const int rl = i*16 + (l >> 4)*4 + v;  // row local to wave 0..63
        float y0 = acc[i][0][v] + bv4[0];
        float y1 = acc[i][1][v] + bv4[1];
        float y2 = acc[i][2][v] + bv4[2];
        float y3 = acc[i][3][v] + bv4[3];
        const float ph = (float)pos_h[r];
        const float pw = (float)pos_w[r];
        float s1,c1,s2,c2,s3,c3,s4,c4;
        __sincosf(ph*f1, &s1, &c1);
        __sincosf(ph*f2, &s2, &c2);
        __sincosf(pw*f1, &s3, &c3);
        __sincosf(pw*f2, &s4, &c4);
        float z[4];
        z[0] = y0*c1 - y1*s1;
        z[1] = y1*c2 + y0*s2;
        z[2] = y2*c3 - y3*s3;
        z[3] = y3*c4 + y2*s4;
        if (t == 0) {
          const float QS = 0.18033688011112042f;   // 0.125 * log2(e)
          z[0]*=QS; z[1]*=QS; z[2]*=QS; z[3]*=QS;
        }
        #pragma unroll
        for (int j = 0; j < 4; j++) {
          const int cl = dd0 + j*16;           // col local 0..63
          Ts[rl*72 + (((cl >> 3) ^ (rl & 7)) << 3) + (cl & 7)] =
              __float2bfloat16(z[j]);
        }
      }
    }
  }
  __syncthreads();                           // ds_writes visible (in-block)

  if (t == 2) {
    const int n0 = (row0 + wm) & 1023;
    const int bp = (row0 + wm) >> 10;
    const size_t gbase = (size_t)(bp*12 + h) * 65536;   // [bh][64][1024]
    #pragma unroll
    for (int dr = 0; dr < 8; dr++) {
      const int dl = dr*8 + (l >> 3);
      const int c  = l & 7;                  // logical 8-elem chunk
      uint4 vv = *(const uint4*)&Ts[dl*72 + ((c ^ (dl & 7)) << 3)];
      *(uint4*)&Vtb[gbase + (size_t)dl*1024 + n0 + c*8] = vv;
    }
  } else {
    bf16* dst = (t == 0) ? Qp : Kp;
    const int rg0 = row0 + wm;               // 64-row block, one bp
    const int bp  = rg0 >> 10;
    const int nb  = rg0 & 1023;
    const size_t gbase = (size_t)(bp*12 + h) * 65536;   // [bh][1024][64]
    #pragma unroll
    for (int dr = 0; dr < 8; dr++) {
      const int rl = dr*8 + (l >> 3);
      const int c  = l & 7;
      uint4 vv = *(const uint4*)&Ts[rl*72 + ((c ^ (rl & 7)) << 3)];
      *(uint4*)&dst[gbase + (size_t)(nb + rl)*64 + c*8] = vv;
    }
  }
}

// ---------------------------------------------------------------------------
// MFMA flash attention. Round-10: BARRIER-FREE, L2-direct K/V.
// FIX vs round-9: K fragment base uses d-offset g*8 (chunk g, 8 elems),
// NOT g*32 — the round-9 typo read past the row for g>=1 (absmax 2.8e-2).
// Semantics now exactly match the verified swizzled-LDS read:
//   K frag elem = K[kt*64 + nt*16 + (l&15)][ss*32 + g*8 + j].
// ---------------------------------------------------------------------------
__global__ __launch_bounds__(512, 4) void attn_mfma(
    const bf16* __restrict__ Qp, const bf16* __restrict__ Kp,
    const bf16* __restrict__ Vtb, bf16* __restrict__ ao)
{
  __shared__ __align__(16) bf16 Ps[128*64];  // P, per-wave 16-row regions
  const int tid = threadIdx.x;
  const int l   = tid & 63;
  const int w   = tid >> 6;                  // 0..7

  const int nwg = gridDim.x * gridDim.y;
  const int bid = blockIdx.y * gridDim.x + blockIdx.x;
  const int lb  = xcd_swizzle(bid, nwg);     // bh-major logical order
  const int qt  = lb & 7;                    // 0..7 (128-row q tiles)
  const int bh  = lb >> 3;                   // chunk-local b*12 + h
  const size_t base = (size_t)bh * 65536;

  const int g    = l >> 4;                   // lane quarter
  const int qrow = w*16 + (l & 15);          // this lane's q-row (local)

  // Q fragments: direct global read (one-time, coalesced 128B rows)
  bf16x8 af[2];
  #pragma unroll
  for (int s = 0; s < 2; s++)
    af[s] = *(const bf16x8*)(Qp + base +
                (size_t)(qt*128 + qrow)*64 + (s*4 + g)*8);

  bf16x8 ones;
  #pragma unroll
  for (int i = 0; i < 8; i++) ones[i] = (__bf16)1.0f;

  float m_i = -3.0e38f;                      // per-lane, q = qrow
  f32x4 l_acc = {};                          // denominators, o layout
  f32x4 o[4] = {};                           // q-local=g*4+v, d=ntd*16+(l&15)

  const bf16* Kb = Kp  + base + (size_t)(l & 15)*64 + g*8;       // FIXED: g*8
  const bf16* Vb = Vtb + base + (size_t)(l & 15)*1024 + g*8;

  for (int kt = 0; kt < 16; kt++) {
    // ---- K fragments for this tile: 8 direct loads (L2-hot) ----
    bf16x8 kf[4][2];
    #pragma unroll
    for (int nt = 0; nt < 4; nt++)
      #pragma unroll
      for (int ss = 0; ss < 2; ss++)
        kf[nt][ss] = *(const bf16x8*)(Kb +
            (size_t)(kt*64 + nt*16)*64 + ss*32);

    // ---- S^T = K . Q^T : s[nt][v] = S[k = nt*16 + 4g + v][q = qrow] ----
    f32x4 s[4];
    __builtin_amdgcn_s_setprio(1);
    #pragma unroll
    for (int nt = 0; nt < 4; nt++) {
      f32x4 a = {};
      a = __builtin_amdgcn_mfma_f32_16x16x32_bf16(kf[nt][0], af[0], a, 0,0,0);
      a = __builtin_amdgcn_mfma_f32_16x16x32_bf16(kf[nt][1], af[1], a, 0,0,0);
      s[nt] = a;
    }
    __builtin_amdgcn_s_setprio(0);

    // ---- online softmax (log2 domain), per-lane q-row ----
    float a0 = fmaxf(fmaxf(s[0][0], s[0][1]), s[0][2]);
    float a1 = fmaxf(fmaxf(s[0][3], s[1][0]), s[1][1]);
    float a2 = fmaxf(fmaxf(s[1][2], s[1][3]), s[2][0]);
    float a3 = fmaxf(fmaxf(s[2][1], s[2][2]), s[2][3]);
    float a4 = fmaxf(fmaxf(s[3][0], s[3][1]), s[3][2]);
    float b0 = fmaxf(fmaxf(a0, a1), a2);
    float b1 = fmaxf(fmaxf(a3, a4), s[3][3]);
    float mloc = fmaxf(b0, b1);
    mloc = fmaxf(mloc, __shfl_xor(mloc, 16));
    const float m0 = fmaxf(mloc, __shfl_xor(mloc, 32));

    if (!__all(m0 - m_i <= 8.0f)) {          // rescale (rare after tile 0)
      const float mx = fmaxf(m_i, m0);
      const float alpha = exp2f(m_i - mx);
      m_i = mx;
      float a_o[4];
      #pragma unroll
      for (int v = 0; v < 4; v++)            // alpha for o's q-local = 4g+v
        a_o[v] = __shfl(alpha, (l & 48) | ((g << 2) + v));
      #pragma unroll
      for (int v = 0; v < 4; v++) {
        l_acc[v] *= a_o[v];
        #pragma unroll
        for (int nt = 0; nt < 4; nt++) o[nt][v] *= a_o[v];
      }
    }

    // ---- P = 2^(S - m), pack to bf16, b64 store into Ps (wave-private) ----
    #pragma unroll
    for (int nt = 0; nt < 4; nt++) {
      const float p0 = exp2f(s[nt][0] - m_i);
      const float p1 = exp2f(s[nt][1] - m_i);
      const float p2 = exp2f(s[nt][2] - m_i);
      const float p3 = exp2f(s[nt][3] - m_i);
      const int k0 = nt*16 + (g << 2);       // 4 consecutive k
      const int ch = (k0 >> 3) ^ (qrow & 7);
      uint2 uu;
      uu.x = pk2(p0, p1);
      uu.y = pk2(p2, p3);
      *(uint2*)&Ps[qrow*64 + ch*8 + (k0 & 7)] = uu;
    }

    // ---- PV + l: o[q][d] += P[q][k] V^T[d][k]; l_acc += P . 1 ----
    __builtin_amdgcn_s_setprio(1);
    #pragma unroll
    for (int ss = 0; ss < 2; ss++) {
      const int pch  = (ss*4 + g) ^ (qrow & 7);
      bf16x8 pa = *(const bf16x8*)&Ps[qrow*64 + pch*8];
      l_acc = __builtin_amdgcn_mfma_f32_16x16x32_bf16(pa, ones, l_acc, 0,0,0);
      #pragma unroll
      for (int ntd = 0; ntd < 4; ntd++) {
        bf16x8 vb = *(const bf16x8*)(Vb +
            (size_t)(ntd*16)*1024 + kt*64 + ss*32);
        o[ntd] = __builtin_amdgcn_mfma_f32_16x16x32_bf16(pa, vb, o[ntd], 0,0,0);
      }
    }
    __builtin_amdgcn_s_setprio(0);
  }

  // ---- epilogue: 1/l in-place (o layout), re-tile through Ps (wave-
  //      private rows, intra-wave ordering only), 16B coalesced stores ----
  const int b = bh / 12, h = bh - b*12;
  #pragma unroll
  for (int v = 0; v < 4; v++) {
    const float invv = 1.0f / l_acc[v];
    const int rl = g*4 + v;                  // 0..15 local row
    #pragma unroll
    for (int ntd = 0; ntd < 4; ntd++) {
      const int cl = ntd*16 + (l & 15);      // 0..63 local col
      Ps[(w*16 + rl)*64 + (((cl >> 3) ^ (rl & 7)) << 3) + (cl & 7)] =
          __float2bfloat16(o[ntd][v] * invv);
    }
  }
  #pragma unroll
  for (int e = 0; e < 2; e++) {
    const int rl = e*8 + (l >> 3);
    const int c  = l & 7;
    uint4 vv = *(const uint4*)&Ps[(w*16 + rl)*64 + ((c ^ (rl & 7)) << 3)];
    const int r = qt*128 + w*16 + rl;
    *(uint4*)&ao[((size_t)(b*1024 + r)) * 768 + h*64 + c*8] = vv;
  }
}

// ---------------------------------------------------------------------------
// Plain MFMA NT-GEMM + bias (proj). global_load_lds staging + XCD swizzle.
// ---------------------------------------------------------------------------
__global__ __launch_bounds__(256) void gemm_mfma(
    const bf16* __restrict__ Ab, const bf16* __restrict__ WT,
    const void* __restrict__ bias, void* __restrict__ Cout,
    const int Nd, const int K, const int c_row_off,
    const int* __restrict__ flag, const int bias_mode, const int c_mode)
{
  const int fl = *flag;
  const bool bbf = (bias_mode == 2) ? (fl != 0) : (bias_mode != 0);
  const bool cbf = (c_mode == 2) ? (fl != 0) : (c_mode != 0);

  __shared__ __align__(16) unsigned short As[128*64];
  __shared__ __align__(16) unsigned short Bs[128*64];

  const int tid = threadIdx.x;
  const int l   = tid & 63;
  const int w   = tid >> 6;
  const int wm  = (w & 1) * 64;
  const int wn  = (w >> 1) * 64;

  const int nwg = gridDim.x * gridDim.y;
  const int bid = blockIdx.y * gridDim.x + blockIdx.x;
  const int lb  = xcd_swizzle(bid, nwg);
  const int gy  = gridDim.y;
  const int brow = lb / gy;
  const int bcol = lb - brow * gy;
  const int row0 = brow * 128;
  const int col0 = bcol * 128;

  const int srow = w*8 + (l >> 3);
  const int sch  = (l & 7) ^ (l >> 3);
  const bf16* Ast = Ab + (size_t)(row0 + srow) * K + sch * 8;
  const bf16* Bst = WT + (size_t)(col0 + srow) * K + sch * 8;

  f32x4 acc[4][4] = {};

  for (int k0 = 0; k0 < K; k0 += 64) {
    __syncthreads();
    #pragma unroll
    for (int i = 0; i < 4; i++) {
      gload16(Ast + (size_t)i*32*K + k0, As + (i*32 + w*8)*64);
      gload16(Bst + (size_t)i*32*K + k0, Bs + (i*32 + w*8)*64);
    }
    __syncthreads();
    #pragma unroll
    for (int s = 0; s < 2; s++) {
      bf16x8 af[4], bg[4];
      const int ch = (s*4 + (l >> 4)) ^ (l & 7);
      #pragma unroll
      for (int i = 0; i < 4; i++) {
        const int rowm = wm + i*16 + (l & 15);
        const int rown = wn + i*16 + (l & 15);
        af[i] = *(const bf16x8*)&As[rowm*64 + ch*8];
        bg[i] = *(const bf16x8*)&Bs[rown*64 + ch*8];
      }
      #pragma unroll
      for (int i = 0; i < 4; i++)
        #pragma unroll
        for (int j = 0; j < 4; j++)
          acc[i][j] = __builtin_amdgcn_mfma_f32_16x16x32_bf16(
                          af[i], bg[j], acc[i][j], 0, 0, 0);
    }
  }

  const int cn    = col0 + wn + (l & 15);
  const int rbase = c_row_off + row0 + wm + (l >> 4) * 4;
  #pragma unroll
  for (int j = 0; j < 4; j++) {
    const int col = cn + j*16;
    const float bval = bbf ? tof(((const bf16*)bias)[col])
                           : ((const float*)bias)[col];
    #pragma unroll
    for (int i = 0; i < 4; i++) {
      #pragma unroll
      for (int v = 0; v < 4; v++) {
        const size_t r = (size_t)(rbase + i*16 + v);
        const float val = acc[i][j][v] + bval;
        if (cbf) ((bf16*)Cout)[r * Nd + col] = __float2bfloat16(val);
        else     ((float*)Cout)[r * Nd + col] = val;
      }
    }
  }
}

// ---------------------------------------------------------------------------
// ws: flag(256B) | WqkvT 3.54MB | WprojT 1.18MB |
//     xb | Qp | Kp | Vt | ao  (each CB*1.57MB)
// ---------------------------------------------------------------------------
extern "C" void kernel_launch(void* const* d_in, const int* in_sizes, int n_in,
                              void* d_out, int out_size, void* d_ws, size_t ws_size,
                              hipStream_t stream)
{
  (void)in_sizes; (void)n_in; (void)out_size;
  const void* x     = d_in[0];
  const void* Wqkv  = d_in[1];
  const void* bqkv  = d_in[2];
  const void* Wproj = d_in[3];
  const void* bproj = d_in[4];
  const int*  pos_h = (const int*)d_in[5];
  const int*  pos_w = (const int*)d_in[6];

  int* flag = (int*)d_ws;
  char* p = (char*)d_ws + 256;
  bf16* WqkvT  = (bf16*)p; p += (size_t)QC_ * C_ * 2;
  bf16* WprojT = (bf16*)p; p += (size_t)C_ * C_ * 2;

  const size_t fixed = 256 + (size_t)QC_*C_*2 + (size_t)C_*C_*2;
  const size_t perb  = 5 * (size_t)N_ * C_ * 2;   // xb,Qp,Kp,Vt,ao per batch
  int CB = 16;
  if (ws_size < fixed + 16*perb) CB = 8;
  if (ws_size < fixed + 8*perb)  CB = 4;
  if (ws_size < fixed + 4*perb)  CB = 2;
  if (ws_size < fixed + 2*perb)  CB = 1;
  const int Mc = CB * N_;
  const size_t tsz = (size_t)Mc * C_;

  bf16* xb  = (bf16*)p;
  bf16* Qp  = xb  + tsz;
  bf16* Kp  = Qp  + tsz;
  bf16* Vtb = Kp  + tsz;
  bf16* ao  = Vtb + tsz;

  detect_dtype<<<1, 256, 0, stream>>>((const unsigned*)x, flag);
  wt_cvt<<<dim3(QC_/32, C_/32), 256, 0, stream>>>(Wqkv, WqkvT, C_, QC_, flag);
  wt_cvt<<<dim3(C_/32,  C_/32), 256, 0, stream>>>(Wproj, WprojT, C_, C_, flag);

  for (int c0 = 0; c0 < B_; c0 += CB) {
    const int n4 = Mc * C_ / 4;
    cvt_x<<<(n4 + 255)/256, 256, 0, stream>>>(x, xb, flag, n4, c0 * N_ * C_ / 4);
    gemm_qkv_rope<<<dim3(Mc/128, QC_/128), 256, 0, stream>>>(
        xb, WqkvT, bqkv, Qp, Kp, Vtb, flag,
        pos_h + (size_t)c0*N_, pos_w + (size_t)c0*N_);
    attn_mfma<<<dim3(N_/128, CB*H_), 512, 0, stream>>>(Qp, Kp, Vtb, ao);
    gemm_mfma<<<dim3(Mc/128, C_/128), 256, 0, stream>>>(
        ao, WprojT, bproj, d_out, C_, C_, c0*N_, flag, 2, 2);
  }
}

// Round 12
// 347.183 us; speedup vs baseline: 1.6735x; 1.6735x over previous
//
#include <hip/hip_runtime.h>
#include <hip/hip_bf16.h>

#define B_ 16
#define N_ 1024
#define C_ 768
#define H_ 12
#define HD_ 64
#define QC_ (3*C_)      // 2304

using bf16 = __hip_bfloat16;
using bf16x8 = __attribute__((ext_vector_type(8))) __bf16;
using f32x4  = __attribute__((ext_vector_type(4))) float;

__device__ __forceinline__ float tof(bf16 v){ return __bfloat162float(v); }

// Async global->LDS 16B DMA. LDS dest is wave-uniform base + lane*16 (linear);
// swizzle is applied on the per-lane GLOBAL address (rule #21).
__device__ __forceinline__ void gload16(const void* g, void* l) {
  __builtin_amdgcn_global_load_lds(
      (const __attribute__((address_space(1))) unsigned int*)g,
      (__attribute__((address_space(3))) unsigned int*)l, 16, 0, 0);
}

// XCD-aware bijective block swizzle (nwg % 8 == 0 holds for all our grids).
__device__ __forceinline__ int xcd_swizzle(int bid, int nwg) {
  return (bid & 7) * (nwg >> 3) + (bid >> 3);
}

// pack two f32 -> one u32 of 2 bf16
__device__ __forceinline__ unsigned pk2(float a, float b) {
  unsigned ua = (unsigned)__bfloat16_as_ushort(__float2bfloat16(a));
  unsigned ub = (unsigned)__bfloat16_as_ushort(__float2bfloat16(b));
  return ua | (ub << 16);
}

// ---------------------------------------------------------------------------
// Input-dtype detector (1=bf16, 0=fp32) from bits 14:7 of sampled words.
// ---------------------------------------------------------------------------
__global__ __launch_bounds__(256) void detect_dtype(
    const unsigned* __restrict__ x32, int* __restrict__ flag)
{
  __shared__ int cnt;
  if (threadIdx.x == 0) cnt = 0;
  __syncthreads();
  int local = 0;
  #pragma unroll
  for (int i = 0; i < 16; i++) {
    unsigned u = x32[threadIdx.x * 16 + i * 4096];
    unsigned e = (u >> 7) & 0xFF;
    local += (e >= 110 && e <= 140) ? 1 : 0;
  }
  atomicAdd(&cnt, local);
  __syncthreads();
  if (threadIdx.x == 0) *flag = (cnt > 2048) ? 1 : 0;
}

// ---------------------------------------------------------------------------
// Cast x (fp32 or bf16 per flag) -> bf16, 4 elems/thread.
// ---------------------------------------------------------------------------
__global__ __launch_bounds__(256) void cvt_x(
    const void* __restrict__ x, bf16* __restrict__ xb,
    const int* __restrict__ flag, const int n4, const int off4)
{
  const int i = blockIdx.x * 256 + threadIdx.x;
  if (i >= n4) return;
  if (*flag) {
    ((uint2*)xb)[i] = ((const uint2*)x)[off4 + i];
  } else {
    float4 v = ((const float4*)x)[off4 + i];
    xb[i*4+0] = __float2bfloat16(v.x);
    xb[i*4+1] = __float2bfloat16(v.y);
    xb[i*4+2] = __float2bfloat16(v.z);
    xb[i*4+3] = __float2bfloat16(v.w);
  }
}

// ---------------------------------------------------------------------------
// WT[n][k] (bf16) = W[k][n] (dtype per flag). Tiled 32x32 transpose.
// ---------------------------------------------------------------------------
__global__ __launch_bounds__(256) void wt_cvt(
    const void* __restrict__ W, bf16* __restrict__ WT,
    const int K, const int Nd, const int* __restrict__ flag)
{
  __shared__ float t[32][33];
  const int fl = *flag;
  const int n0 = blockIdx.x * 32, k0 = blockIdx.y * 32;
  const int tx = threadIdx.x & 31, ty = threadIdx.x >> 5;   // 32 x 8
  for (int kk = ty; kk < 32; kk += 8) {
    const size_t gi = (size_t)(k0 + kk) * Nd + (n0 + tx);
    t[kk][tx] = fl ? tof(((const bf16*)W)[gi]) : ((const float*)W)[gi];
  }
  __syncthreads();
  for (int nn = ty; nn < 32; nn += 8)
    WT[(size_t)(n0 + nn) * K + (k0 + tx)] = __float2bfloat16(t[tx][nn]);
}

// ---------------------------------------------------------------------------
// Fused qkv GEMM + bias + RoPE + layout scatter. (unchanged, verified)
// Q is scaled by 0.125 * log2(e) so attention S arrives in log2 domain.
// ---------------------------------------------------------------------------
__global__ __launch_bounds__(256) void gemm_qkv_rope(
    const bf16* __restrict__ Ab, const bf16* __restrict__ WT,
    const void* __restrict__ bias, bf16* __restrict__ Qp,
    bf16* __restrict__ Kp, bf16* __restrict__ Vtb,
    const int* __restrict__ flag,
    const int* __restrict__ pos_h, const int* __restrict__ pos_w)
{
  const int K = C_;
  const bool bbf = (*flag != 0);

  __shared__ __align__(16) char smem[36864];
  unsigned short* As = (unsigned short*)smem;
  unsigned short* Bs = (unsigned short*)(smem + 16384);

  const int tid = threadIdx.x;
  const int l   = tid & 63;
  const int w   = tid >> 6;
  const int wm  = (w & 1) * 64;
  const int wn  = (w >> 1) * 64;

  const int nwg = gridDim.x * gridDim.y;
  const int bid = blockIdx.y * gridDim.x + blockIdx.x;
  const int lb  = xcd_swizzle(bid, nwg);
  const int gy  = gridDim.y;                 // 18
  const int brow = lb / gy;
  const int bcol = lb - brow * gy;
  const int row0 = brow * 128;
  const int col0 = bcol * 128;

  const int srow = w*8 + (l >> 3);
  const int sch  = (l & 7) ^ (l >> 3);
  const bf16* Ast = Ab + (size_t)(row0 + srow) * K + sch * 8;
  const bf16* Bst = WT + (size_t)(col0 + srow) * K + sch * 8;

  f32x4 acc[4][4] = {};

  for (int k0 = 0; k0 < K; k0 += 64) {
    __syncthreads();                         // prev iter's LDS reads done
    #pragma unroll
    for (int i = 0; i < 4; i++) {
      gload16(Ast + (size_t)i*32*K + k0, As + (i*32 + w*8)*64);
      gload16(Bst + (size_t)i*32*K + k0, Bs + (i*32 + w*8)*64);
    }
    __syncthreads();                         // drains vmcnt -> LDS ready
    #pragma unroll
    for (int s = 0; s < 2; s++) {
      bf16x8 af[4], bg[4];
      const int ch = (s*4 + (l >> 4)) ^ (l & 7);
      #pragma unroll
      for (int i = 0; i < 4; i++) {
        const int rowm = wm + i*16 + (l & 15);
        const int rown = wn + i*16 + (l & 15);
        af[i] = *(const bf16x8*)&As[rowm*64 + ch*8];
        bg[i] = *(const bf16x8*)&Bs[rown*64 + ch*8];
      }
      #pragma unroll
      for (int i = 0; i < 4; i++)
        #pragma unroll
        for (int j = 0; j < 4; j++)
          acc[i][j] = __builtin_amdgcn_mfma_f32_16x16x32_bf16(
                          af[i], bg[j], acc[i][j], 0, 0, 0);
    }
  }

  // ---- fused epilogue ----
  const int colbase = col0 + wn;            // multiple of 64
  const int t   = colbase / 768;            // 0=q 1=k 2=v (block-uniform)
  const int h   = (colbase % 768) >> 6;     // head (wave-uniform)
  const int dd0 = l & 15;
  float bv4[4];
  #pragma unroll
  for (int j = 0; j < 4; j++) {
    const int c = colbase + dd0 + j*16;
    bv4[j] = bbf ? tof(((const bf16*)bias)[c]) : ((const float*)bias)[c];
  }
  const int rb = row0 + wm + (l >> 4) * 4;

  __syncthreads();                           // As/Bs dead for ALL waves
  bf16* Ts = (bf16*)(smem + w * 9216);       // 64 rows x 72 elems (144 B)

  if (t == 2) {
    #pragma unroll
    for (int i = 0; i < 4; i++) {
      #pragma unroll
      for (int v = 0; v < 4; v++) {
        const int nl = i*16 + ((l >> 4) << 2) + v;   // n_local 0..63
        #pragma unroll
        for (int j = 0; j < 4; j++) {
          const int dl = dd0 + j*16;                 // d_local 0..63
          const float y = acc[i][j][v] + bv4[j];
          Ts[dl*72 + (((nl >> 3) ^ (dl & 7)) << 3) + (nl & 7)] =
              __float2bfloat16(y);
        }
      }
    }
  } else {
    const int fi  = dd0 >> 1;
    const float LOG2B = 13.287712379549449f;  // log2(10000)
    const float f1 = exp2f(-LOG2B * (float)fi       * (1.0f/16.0f));
    const float f2 = exp2f(-LOG2B * (float)(fi + 8) * (1.0f/16.0f));
    #pragma unroll
    for (int i = 0; i < 4; i++) {
      #pragma unroll
      for (int v = 0; v < 4; v++) {
        const int r  = rb + i*16 + v;          // chunk-local row (global)
        const int rl = i*16 + (l >> 4)*4 + v;  // row local to wave 0..63
        float y0 = acc[i][0][v] + bv4[0];
        float y1 = acc[i][1][v] + bv4[1];
        float y2 = acc[i][2][v] + bv4[2];
        float y3 = acc[i][3][v] + bv4[3];
        const float ph = (float)pos_h[r];
        const float pw = (float)pos_w[r];
        float s1,c1,s2,c2,s3,c3,s4,c4;
        __sincosf(ph*f1, &s1, &c1);
        __sincosf(ph*f2, &s2, &c2);
        __sincosf(pw*f1, &s3, &c3);
        __sincosf(pw*f2, &s4, &c4);
        float z[4];
        z[0] = y0*c1 - y1*s1;
        z[1] = y1*c2 + y0*s2;
        z[2] = y2*c3 - y3*s3;
        z[3] = y3*c4 + y2*s4;
        if (t == 0) {
          const float QS = 0.18033688011112042f;   // 0.125 * log2(e)
          z[0]*=QS; z[1]*=QS; z[2]*=QS; z[3]*=QS;
        }
        #pragma unroll
        for (int j = 0; j < 4; j++) {
          const int cl = dd0 + j*16;           // col local 0..63
          Ts[rl*72 + (((cl >> 3) ^ (rl & 7)) << 3) + (cl & 7)] =
              __float2bfloat16(z[j]);
        }
      }
    }
  }
  __syncthreads();                           // ds_writes visible (in-block)

  if (t == 2) {
    const int n0 = (row0 + wm) & 1023;
    const int bp = (row0 + wm) >> 10;
    const size_t gbase = (size_t)(bp*12 + h) * 65536;   // [bh][64][1024]
    #pragma unroll
    for (int dr = 0; dr < 8; dr++) {
      const int dl = dr*8 + (l >> 3);
      const int c  = l & 7;                  // logical 8-elem chunk
      uint4 vv = *(const uint4*)&Ts[dl*72 + ((c ^ (dl & 7)) << 3)];
      *(uint4*)&Vtb[gbase + (size_t)dl*1024 + n0 + c*8] = vv;
    }
  } else {
    bf16* dst = (t == 0) ? Qp : Kp;
    const int rg0 = row0 + wm;               // 64-row block, one bp
    const int bp  = rg0 >> 10;
    const int nb  = rg0 & 1023;
    const size_t gbase = (size_t)(bp*12 + h) * 65536;   // [bh][1024][64]
    #pragma unroll
    for (int dr = 0; dr < 8; dr++) {
      const int rl = dr*8 + (l >> 3);
      const int c  = l & 7;
      uint4 vv = *(const uint4*)&Ts[rl*72 + ((c ^ (rl & 7)) << 3)];
      *(uint4*)&dst[gbase + (size_t)(nb + rl)*64 + c*8] = vv;
    }
  }
}

// ---------------------------------------------------------------------------
// MFMA flash attention. Round-12 (resubmit of round-11; infra failed, not
// the kernel): verified round-7 staged structure + kt loop unrolled x2 so
// cur = kt&1 is compile-time per copy (buffer-pointer selects vanish; LDS
// offsets become immediates). 512-thread blocks (8 waves), q-tile 128;
// 2-phase double-buffered K/V with counted vmcnt(2); swapped QK^T;
// log2-domain softmax; ones-MFMA denominator.
// ---------------------------------------------------------------------------
__global__ __launch_bounds__(512) void attn_mfma(
    const bf16* __restrict__ Qp, const bf16* __restrict__ Kp,
    const bf16* __restrict__ Vtb, bf16* __restrict__ ao)
{
  __shared__ __align__(16) bf16 QPs[128*64];    // Qs (prologue) then Ps
  __shared__ __align__(16) bf16 Ks[2][64*64];   // double-buffered K
  __shared__ __align__(16) bf16 Vs[2][64*64];   // double-buffered V^T
  bf16* Qs = QPs;
  bf16* Ps = QPs;
  const int tid = threadIdx.x;
  const int l   = tid & 63;
  const int w   = tid >> 6;                  // 0..7

  const int nwg = gridDim.x * gridDim.y;
  const int bid = blockIdx.y * gridDim.x + blockIdx.x;
  const int lb  = xcd_swizzle(bid, nwg);     // bh-major logical order
  const int qt  = lb & 7;                    // 0..7 (128-row q tiles)
  const int bh  = lb >> 3;                   // chunk-local b*12 + h
  const size_t base = (size_t)bh * 65536;

  const int srow = w*8 + (l >> 3);           // 0..63 across 8 waves
  const int sch  = (l & 7) ^ (l >> 3);
  const bf16* Qst = Qp  + base + (size_t)(qt*128 + srow)*64 + sch*8;
  const bf16* Kst = Kp  + base + (size_t)srow*64   + sch*8;
  const bf16* Vst = Vtb + base + (size_t)srow*1024 + sch*8;

  // stage K/V tile tt into buffer b: ONE K DMA + ONE V DMA per wave
  #define STAGE_KV(tt, b)                                                    \
    { gload16(Kst + (size_t)(tt)*64*64, Ks[b] + (w*8)*64);                   \
      gload16(Vst + (size_t)(tt)*64,    Vs[b] + (w*8)*64); }

  // prologue: Q (2 DMAs/wave, 128 rows) + tile0 -> full drain, read Q frags,
  // stage tile1
  #pragma unroll
  for (int i = 0; i < 2; i++)
    gload16(Qst + (size_t)i*64*64, Qs + (i*64 + w*8)*64);
  STAGE_KV(0, 0);
  __syncthreads();                           // drains vmcnt -> Q + tile0 ready

  bf16x8 af[2];
  {
    const int row = w*16 + (l & 15);         // 0..127
    #pragma unroll
    for (int s = 0; s < 2; s++) {
      const int ch = (s*4 + (l >> 4)) ^ (row & 7);
      af[s] = *(const bf16x8*)&Qs[row*64 + ch*8];
    }
  }
  STAGE_KV(1, 1);                            // tile1 in flight (2 DMAs)

  bf16x8 ones;
  #pragma unroll
  for (int i = 0; i < 8; i++) ones[i] = (__bf16)1.0f;

  float m_i = -3.0e38f;                      // per-lane, q = w*16 + (l&15)
  f32x4 l_acc = {};                          // denominators, o layout
  f32x4 o[4] = {};                           // q-local=(l>>4)*4+v, d=ntd*16+(l&15)

  const int g    = l >> 4;                   // lane quarter
  const int qrow = w*16 + (l & 15);          // this lane's q-row (local)

  #pragma unroll 2
  for (int kt = 0; kt < 16; kt++) {
    const int cur = kt & 1;
    if (kt > 0) {
      // tile kt's 2 DMAs done (kt+1's 2 stay in flight); then all-wave sync
      if (kt < 15) { asm volatile("s_waitcnt vmcnt(2)" ::: "memory"); }
      else         { asm volatile("s_waitcnt vmcnt(0)" ::: "memory"); }
      __builtin_amdgcn_s_barrier();
      asm volatile("" ::: "memory");
    }
    const bf16* Ksb = Ks[cur];
    const bf16* Vsb = Vs[cur];

    // ---- S^T = K . Q^T : s[nt][v] = S[k = nt*16 + 4g + v][q = qrow] ----
    f32x4 s[4];
    __builtin_amdgcn_s_setprio(1);
    #pragma unroll
    for (int nt = 0; nt < 4; nt++) {
      f32x4 a = {};
      const int nrow = nt*16 + (l & 15);
      #pragma unroll
      for (int ss = 0; ss < 2; ss++) {
        const int ch = (ss*4 + (l >> 4)) ^ (nrow & 7);
        bf16x8 bg = *(const bf16x8*)&Ksb[nrow*64 + ch*8];
        a = __builtin_amdgcn_mfma_f32_16x16x32_bf16(bg, af[ss], a, 0, 0, 0);
      }
      s[nt] = a;
    }
    __builtin_amdgcn_s_setprio(0);

    // ---- online softmax (log2 domain), per-lane q-row ----
    float a0 = fmaxf(fmaxf(s[0][0], s[0][1]), s[0][2]);
    float a1 = fmaxf(fmaxf(s[0][3], s[1][0]), s[1][1]);
    float a2 = fmaxf(fmaxf(s[1][2], s[1][3]), s[2][0]);
    float a3 = fmaxf(fmaxf(s[2][1], s[2][2]), s[2][3]);
    float a4 = fmaxf(fmaxf(s[3][0], s[3][1]), s[3][2]);
    float b0 = fmaxf(fmaxf(a0, a1), a2);
    float b1 = fmaxf(fmaxf(a3, a4), s[3][3]);
    float mloc = fmaxf(b0, b1);
    mloc = fmaxf(mloc, __shfl_xor(mloc, 16));
    const float m0 = fmaxf(mloc, __shfl_xor(mloc, 32));

    if (!__all(m0 - m_i <= 8.0f)) {          // rescale (rare after tile 0)
      const float mx = fmaxf(m_i, m0);
      const float alpha = exp2f(m_i - mx);
      m_i = mx;
      float a_o[4];
      #pragma unroll
      for (int v = 0; v < 4; v++)            // alpha for o's q-local = 4g+v
        a_o[v] = __shfl(alpha, (l & 48) | ((g << 2) + v));
      #pragma unroll
      for (int v = 0; v < 4; v++) {
        l_acc[v] *= a_o[v];
        #pragma unroll
        for (int nt = 0; nt < 4; nt++) o[nt][v] *= a_o[v];
      }
    }

    // ---- P = 2^(S - m), pack to bf16, b64 store into Ps (wave-private) ----
    #pragma unroll
    for (int nt = 0; nt < 4; nt++) {
      const float p0 = exp2f(s[nt][0] - m_i);
      const float p1 = exp2f(s[nt][1] - m_i);
      const float p2 = exp2f(s[nt][2] - m_i);
      const float p3 = exp2f(s[nt][3] - m_i);
      const int k0 = nt*16 + (g << 2);       // 4 consecutive k
      const int ch = (k0 >> 3) ^ (qrow & 7);
      uint2 uu;
      uu.x = pk2(p0, p1);
      uu.y = pk2(p2, p3);
      *(uint2*)&Ps[qrow*64 + ch*8 + (k0 & 7)] = uu;
    }

    // ---- PV + l: o[q][d] += P[q][k] V^T[d][k]; l_acc += P . 1 ----
    __builtin_amdgcn_s_setprio(1);
    #pragma unroll
    for (int ss = 0; ss < 2; ss++) {
      const int pch  = (ss*4 + g) ^ (qrow & 7);
      bf16x8 pa = *(const bf16x8*)&Ps[qrow*64 + pch*8];
      l_acc = __builtin_amdgcn_mfma_f32_16x16x32_bf16(pa, ones, l_acc, 0,0,0);
      #pragma unroll
      for (int ntd = 0; ntd < 4; ntd++) {
        const int drow = ntd*16 + (l & 15);
        const int vch  = (ss*4 + (l >> 4)) ^ (drow & 7);
        bf16x8 vb = *(const bf16x8*)&Vsb[drow*64 + vch*8];
        o[ntd] = __builtin_amdgcn_mfma_f32_16x16x32_bf16(pa, vb, o[ntd], 0,0,0);
      }
    }
    __builtin_amdgcn_s_setprio(0);

    // all waves done reading buf[cur] -> safe to overwrite it with kt+2
    asm volatile("" ::: "memory");
    __builtin_amdgcn_s_barrier();
    asm volatile("" ::: "memory");
    if (kt + 2 < 16) STAGE_KV(kt + 2, cur);
  }
  #undef STAGE_KV

  // ---- epilogue: 1/l in-place (o layout), re-tile through Ps (wave-
  //      private rows), 16B coalesced stores ----
  const int b = bh / 12, h = bh - b*12;
  #pragma unroll
  for (int v = 0; v < 4; v++) {
    const float invv = 1.0f / l_acc[v];
    const int rl = g*4 + v;                  // 0..15 local row
    #pragma unroll
    for (int ntd = 0; ntd < 4; ntd++) {
      const int cl = ntd*16 + (l & 15);      // 0..63 local col
      Ps[(w*16 + rl)*64 + (((cl >> 3) ^ (rl & 7)) << 3) + (cl & 7)] =
          __float2bfloat16(o[ntd][v] * invv);
    }
  }
  #pragma unroll
  for (int e = 0; e < 2; e++) {
    const int rl = e*8 + (l >> 3);
    const int c  = l & 7;
    uint4 vv = *(const uint4*)&Ps[(w*16 + rl)*64 + ((c ^ (rl & 7)) << 3)];
    const int r = qt*128 + w*16 + rl;
    *(uint4*)&ao[((size_t)(b*1024 + r)) * 768 + h*64 + c*8] = vv;
  }
}

// ---------------------------------------------------------------------------
// Plain MFMA NT-GEMM + bias (proj). global_load_lds staging + XCD swizzle.
// ---------------------------------------------------------------------------
__global__ __launch_bounds__(256) void gemm_mfma(
    const bf16* __restrict__ Ab, const bf16* __restrict__ WT,
    const void* __restrict__ bias, void* __restrict__ Cout,
    const int Nd, const int K, const int c_row_off,
    const int* __restrict__ flag, const int bias_mode, const int c_mode)
{
  const int fl = *flag;
  const bool bbf = (bias_mode == 2) ? (fl != 0) : (bias_mode != 0);
  const bool cbf = (c_mode == 2) ? (fl != 0) : (c_mode != 0);

  __shared__ __align__(16) unsigned short As[128*64];
  __shared__ __align__(16) unsigned short Bs[128*64];

  const int tid = threadIdx.x;
  const int l   = tid & 63;
  const int w   = tid >> 6;
  const int wm  = (w & 1) * 64;
  const int wn  = (w >> 1) * 64;

  const int nwg = gridDim.x * gridDim.y;
  const int bid = blockIdx.y * gridDim.x + blockIdx.x;
  const int lb  = xcd_swizzle(bid, nwg);
  const int gy  = gridDim.y;
  const int brow = lb / gy;
  const int bcol = lb - brow * gy;
  const int row0 = brow * 128;
  const int col0 = bcol * 128;

  const int srow = w*8 + (l >> 3);
  const int sch  = (l & 7) ^ (l >> 3);
  const bf16* Ast = Ab + (size_t)(row0 + srow) * K + sch * 8;
  const bf16* Bst = WT + (size_t)(col0 + srow) * K + sch * 8;

  f32x4 acc[4][4] = {};

  for (int k0 = 0; k0 < K; k0 += 64) {
    __syncthreads();
    #pragma unroll
    for (int i = 0; i < 4; i++) {
      gload16(Ast + (size_t)i*32*K + k0, As + (i*32 + w*8)*64);
      gload16(Bst + (size_t)i*32*K + k0, Bs + (i*32 + w*8)*64);
    }
    __syncthreads();
    #pragma unroll
    for (int s = 0; s < 2; s++) {
      bf16x8 af[4], bg[4];
      const int ch = (s*4 + (l >> 4)) ^ (l & 7);
      #pragma unroll
      for (int i = 0; i < 4; i++) {
        const int rowm = wm + i*16 + (l & 15);
        const int rown = wn + i*16 + (l & 15);
        af[i] = *(const bf16x8*)&As[rowm*64 + ch*8];
        bg[i] = *(const bf16x8*)&Bs[rown*64 + ch*8];
      }
      #pragma unroll
      for (int i = 0; i < 4; i++)
        #pragma unroll
        for (int j = 0; j < 4; j++)
          acc[i][j] = __builtin_amdgcn_mfma_f32_16x16x32_bf16(
                          af[i], bg[j], acc[i][j], 0, 0, 0);
    }
  }

  const int cn    = col0 + wn + (l & 15);
  const int rbase = c_row_off + row0 + wm + (l >> 4) * 4;
  #pragma unroll
  for (int j = 0; j < 4; j++) {
    const int col = cn + j*16;
    const float bval = bbf ? tof(((const bf16*)bias)[col])
                           : ((const float*)bias)[col];
    #pragma unroll
    for (int i = 0; i < 4; i++) {
      #pragma unroll
      for (int v = 0; v < 4; v++) {
        const size_t r = (size_t)(rbase + i*16 + v);
        const float val = acc[i][j][v] + bval;
        if (cbf) ((bf16*)Cout)[r * Nd + col] = __float2bfloat16(val);
        else     ((float*)Cout)[r * Nd + col] = val;
      }
    }
  }
}

// ---------------------------------------------------------------------------
// ws: flag(256B) | WqkvT 3.54MB | WprojT 1.18MB |
//     xb | Qp | Kp | Vt | ao  (each CB*1.57MB)
// ---------------------------------------------------------------------------
extern "C" void kernel_launch(void* const* d_in, const int* in_sizes, int n_in,
                              void* d_out, int out_size, void* d_ws, size_t ws_size,
                              hipStream_t stream)
{
  (void)in_sizes; (void)n_in; (void)out_size;
  const void* x     = d_in[0];
  const void* Wqkv  = d_in[1];
  const void* bqkv  = d_in[2];
  const void* Wproj = d_in[3];
  const void* bproj = d_in[4];
  const int*  pos_h = (const int*)d_in[5];
  const int*  pos_w = (const int*)d_in[6];

  int* flag = (int*)d_ws;
  char* p = (char*)d_ws + 256;
  bf16* WqkvT  = (bf16*)p; p += (size_t)QC_ * C_ * 2;
  bf16* WprojT = (bf16*)p; p += (size_t)C_ * C_ * 2;

  const size_t fixed = 256 + (size_t)QC_*C_*2 + (size_t)C_*C_*2;
  const size_t perb  = 5 * (size_t)N_ * C_ * 2;   // xb,Qp,Kp,Vt,ao per batch
  int CB = 16;
  if (ws_size < fixed + 16*perb) CB = 8;
  if (ws_size < fixed + 8*perb)  CB = 4;
  if (ws_size < fixed + 4*perb)  CB = 2;
  if (ws_size < fixed + 2*perb)  CB = 1;
  const int Mc = CB * N_;
  const size_t tsz = (size_t)Mc * C_;

  bf16* xb  = (bf16*)p;
  bf16* Qp  = xb  + tsz;
  bf16* Kp  = Qp  + tsz;
  bf16* Vtb = Kp  + tsz;
  bf16* ao  = Vtb + tsz;

  detect_dtype<<<1, 256, 0, stream>>>((const unsigned*)x, flag);
  wt_cvt<<<dim3(QC_/32, C_/32), 256, 0, stream>>>(Wqkv, WqkvT, C_, QC_, flag);
  wt_cvt<<<dim3(C_/32,  C_/32), 256, 0, stream>>>(Wproj, WprojT, C_, C_, flag);

  for (int c0 = 0; c0 < B_; c0 += CB) {
    const int n4 = Mc * C_ / 4;
    cvt_x<<<(n4 + 255)/256, 256, 0, stream>>>(x, xb, flag, n4, c0 * N_ * C_ / 4);
    gemm_qkv_rope<<<dim3(Mc/128, QC_/128), 256, 0, stream>>>(
        xb, WqkvT, bqkv, Qp, Kp, Vtb, flag,
        pos_h + (size_t)c0*N_, pos_w + (size_t)c0*N_);
    attn_mfma<<<dim3(N_/128, CB*H_), 512, 0, stream>>>(Qp, Kp, Vtb, ao);
    gemm_mfma<<<dim3(Mc/128, C_/128), 256, 0, stream>>>(
        ao, WprojT, bproj, d_out, C_, C_, c0*N_, flag, 2, 2);
  }
}

// Round 13
// 343.741 us; speedup vs baseline: 1.6902x; 1.0100x over previous
//
#include <hip/hip_runtime.h>
#include <hip/hip_bf16.h>

#define B_ 16
#define N_ 1024
#define C_ 768
#define H_ 12
#define HD_ 64
#define QC_ (3*C_)      // 2304

using bf16 = __hip_bfloat16;
using bf16x8 = __attribute__((ext_vector_type(8))) __bf16;
using f32x4  = __attribute__((ext_vector_type(4))) float;

__device__ __forceinline__ float tof(bf16 v){ return __bfloat162float(v); }

// Async global->LDS 16B DMA. LDS dest is wave-uniform base + lane*16 (linear);
// swizzle is applied on the per-lane GLOBAL address (rule #21).
__device__ __forceinline__ void gload16(const void* g, void* l) {
  __builtin_amdgcn_global_load_lds(
      (const __attribute__((address_space(1))) unsigned int*)g,
      (__attribute__((address_space(3))) unsigned int*)l, 16, 0, 0);
}

// XCD-aware bijective block swizzle (nwg % 8 == 0 holds for all our grids).
__device__ __forceinline__ int xcd_swizzle(int bid, int nwg) {
  return (bid & 7) * (nwg >> 3) + (bid >> 3);
}

// pack two f32 -> one u32 of 2 bf16
__device__ __forceinline__ unsigned pk2(float a, float b) {
  unsigned ua = (unsigned)__bfloat16_as_ushort(__float2bfloat16(a));
  unsigned ub = (unsigned)__bfloat16_as_ushort(__float2bfloat16(b));
  return ua | (ub << 16);
}

// ---------------------------------------------------------------------------
// Input-dtype detector (1=bf16, 0=fp32) from bits 14:7 of sampled words.
// ---------------------------------------------------------------------------
__global__ __launch_bounds__(256) void detect_dtype(
    const unsigned* __restrict__ x32, int* __restrict__ flag)
{
  __shared__ int cnt;
  if (threadIdx.x == 0) cnt = 0;
  __syncthreads();
  int local = 0;
  #pragma unroll
  for (int i = 0; i < 16; i++) {
    unsigned u = x32[threadIdx.x * 16 + i * 4096];
    unsigned e = (u >> 7) & 0xFF;
    local += (e >= 110 && e <= 140) ? 1 : 0;
  }
  atomicAdd(&cnt, local);
  __syncthreads();
  if (threadIdx.x == 0) *flag = (cnt > 2048) ? 1 : 0;
}

// ---------------------------------------------------------------------------
// Cast x (fp32 or bf16 per flag) -> bf16, 4 elems/thread.
// ---------------------------------------------------------------------------
__global__ __launch_bounds__(256) void cvt_x(
    const void* __restrict__ x, bf16* __restrict__ xb,
    const int* __restrict__ flag, const int n4, const int off4)
{
  const int i = blockIdx.x * 256 + threadIdx.x;
  if (i >= n4) return;
  if (*flag) {
    ((uint2*)xb)[i] = ((const uint2*)x)[off4 + i];
  } else {
    float4 v = ((const float4*)x)[off4 + i];
    xb[i*4+0] = __float2bfloat16(v.x);
    xb[i*4+1] = __float2bfloat16(v.y);
    xb[i*4+2] = __float2bfloat16(v.z);
    xb[i*4+3] = __float2bfloat16(v.w);
  }
}

// ---------------------------------------------------------------------------
// WT[n][k] (bf16) = W[k][n] (dtype per flag). Tiled 32x32 transpose.
// ---------------------------------------------------------------------------
__global__ __launch_bounds__(256) void wt_cvt(
    const void* __restrict__ W, bf16* __restrict__ WT,
    const int K, const int Nd, const int* __restrict__ flag)
{
  __shared__ float t[32][33];
  const int fl = *flag;
  const int n0 = blockIdx.x * 32, k0 = blockIdx.y * 32;
  const int tx = threadIdx.x & 31, ty = threadIdx.x >> 5;   // 32 x 8
  for (int kk = ty; kk < 32; kk += 8) {
    const size_t gi = (size_t)(k0 + kk) * Nd + (n0 + tx);
    t[kk][tx] = fl ? tof(((const bf16*)W)[gi]) : ((const float*)W)[gi];
  }
  __syncthreads();
  for (int nn = ty; nn < 32; nn += 8)
    WT[(size_t)(n0 + nn) * K + (k0 + tx)] = __float2bfloat16(t[tx][nn]);
}

// ---------------------------------------------------------------------------
// Fused qkv GEMM + bias + RoPE + layout scatter. (unchanged, verified)
// Q is scaled by 0.125 * log2(e) so attention S arrives in log2 domain.
// ---------------------------------------------------------------------------
__global__ __launch_bounds__(256) void gemm_qkv_rope(
    const bf16* __restrict__ Ab, const bf16* __restrict__ WT,
    const void* __restrict__ bias, bf16* __restrict__ Qp,
    bf16* __restrict__ Kp, bf16* __restrict__ Vtb,
    const int* __restrict__ flag,
    const int* __restrict__ pos_h, const int* __restrict__ pos_w)
{
  const int K = C_;
  const bool bbf = (*flag != 0);

  __shared__ __align__(16) char smem[36864];
  unsigned short* As = (unsigned short*)smem;
  unsigned short* Bs = (unsigned short*)(smem + 16384);

  const int tid = threadIdx.x;
  const int l   = tid & 63;
  const int w   = tid >> 6;
  const int wm  = (w & 1) * 64;
  const int wn  = (w >> 1) * 64;

  const int nwg = gridDim.x * gridDim.y;
  const int bid = blockIdx.y * gridDim.x + blockIdx.x;
  const int lb  = xcd_swizzle(bid, nwg);
  const int gy  = gridDim.y;                 // 18
  const int brow = lb / gy;
  const int bcol = lb - brow * gy;
  const int row0 = brow * 128;
  const int col0 = bcol * 128;

  const int srow = w*8 + (l >> 3);
  const int sch  = (l & 7) ^ (l >> 3);
  const bf16* Ast = Ab + (size_t)(row0 + srow) * K + sch * 8;
  const bf16* Bst = WT + (size_t)(col0 + srow) * K + sch * 8;

  f32x4 acc[4][4] = {};

  for (int k0 = 0; k0 < K; k0 += 64) {
    __syncthreads();                         // prev iter's LDS reads done
    #pragma unroll
    for (int i = 0; i < 4; i++) {
      gload16(Ast + (size_t)i*32*K + k0, As + (i*32 + w*8)*64);
      gload16(Bst + (size_t)i*32*K + k0, Bs + (i*32 + w*8)*64);
    }
    __syncthreads();                         // drains vmcnt -> LDS ready
    #pragma unroll
    for (int s = 0; s < 2; s++) {
      bf16x8 af[4], bg[4];
      const int ch = (s*4 + (l >> 4)) ^ (l & 7);
      #pragma unroll
      for (int i = 0; i < 4; i++) {
        const int rowm = wm + i*16 + (l & 15);
        const int rown = wn + i*16 + (l & 15);
        af[i] = *(const bf16x8*)&As[rowm*64 + ch*8];
        bg[i] = *(const bf16x8*)&Bs[rown*64 + ch*8];
      }
      #pragma unroll
      for (int i = 0; i < 4; i++)
        #pragma unroll
        for (int j = 0; j < 4; j++)
          acc[i][j] = __builtin_amdgcn_mfma_f32_16x16x32_bf16(
                          af[i], bg[j], acc[i][j], 0, 0, 0);
    }
  }

  // ---- fused epilogue ----
  const int colbase = col0 + wn;            // multiple of 64
  const int t   = colbase / 768;            // 0=q 1=k 2=v (block-uniform)
  const int h   = (colbase % 768) >> 6;     // head (wave-uniform)
  const int dd0 = l & 15;
  float bv4[4];
  #pragma unroll
  for (int j = 0; j < 4; j++) {
    const int c = colbase + dd0 + j*16;
    bv4[j] = bbf ? tof(((const bf16*)bias)[c]) : ((const float*)bias)[c];
  }
  const int rb = row0 + wm + (l >> 4) * 4;

  __syncthreads();                           // As/Bs dead for ALL waves
  bf16* Ts = (bf16*)(smem + w * 9216);       // 64 rows x 72 elems (144 B)

  if (t == 2) {
    #pragma unroll
    for (int i = 0; i < 4; i++) {
      #pragma unroll
      for (int v = 0; v < 4; v++) {
        const int nl = i*16 + ((l >> 4) << 2) + v;   // n_local 0..63
        #pragma unroll
        for (int j = 0; j < 4; j++) {
          const int dl = dd0 + j*16;                 // d_local 0..63
          const float y = acc[i][j][v] + bv4[j];
          Ts[dl*72 + (((nl >> 3) ^ (dl & 7)) << 3) + (nl & 7)] =
              __float2bfloat16(y);
        }
      }
    }
  } else {
    const int fi  = dd0 >> 1;
    const float LOG2B = 13.287712379549449f;  // log2(10000)
    const float f1 = exp2f(-LOG2B * (float)fi       * (1.0f/16.0f));
    const float f2 = exp2f(-LOG2B * (float)(fi + 8) * (1.0f/16.0f));
    #pragma unroll
    for (int i = 0; i < 4; i++) {
      #pragma unroll
      for (int v = 0; v < 4; v++) {
        const int r  = rb + i*16 + v;          // global row
        const int rl = i*16 + (l >> 4)*4 + v;  // row local to wave 0..63
        float y0 = acc[i][0][v] + bv4[0];
        float y1 = acc[i][1][v] + bv4[1];
        float y2 = acc[i][2][v] + bv4[2];
        float y3 = acc[i][3][v] + bv4[3];
        const float ph = (float)pos_h[r];
        const float pw = (float)pos_w[r];
        float s1,c1,s2,c2,s3,c3,s4,c4;
        __sincosf(ph*f1, &s1, &c1);
        __sincosf(ph*f2, &s2, &c2);
        __sincosf(pw*f1, &s3, &c3);
        __sincosf(pw*f2, &s4, &c4);
        float z[4];
        z[0] = y0*c1 - y1*s1;
        z[1] = y1*c2 + y0*s2;
        z[2] = y2*c3 - y3*s3;
        z[3] = y3*c4 + y2*s4;
        if (t == 0) {
          const float QS = 0.18033688011112042f;   // 0.125 * log2(e)
          z[0]*=QS; z[1]*=QS; z[2]*=QS; z[3]*=QS;
        }
        #pragma unroll
        for (int j = 0; j < 4; j++) {
          const int cl = dd0 + j*16;           // col local 0..63
          Ts[rl*72 + (((cl >> 3) ^ (rl & 7)) << 3) + (cl & 7)] =
              __float2bfloat16(z[j]);
        }
      }
    }
  }
  __syncthreads();                           // ds_writes visible (in-block)

  if (t == 2) {
    const int n0 = (row0 + wm) & 1023;
    const int bp = (row0 + wm) >> 10;
    const size_t gbase = (size_t)(bp*12 + h) * 65536;   // [bh][64][1024]
    #pragma unroll
    for (int dr = 0; dr < 8; dr++) {
      const int dl = dr*8 + (l >> 3);
      const int c  = l & 7;                  // logical 8-elem chunk
      uint4 vv = *(const uint4*)&Ts[dl*72 + ((c ^ (dl & 7)) << 3)];
      *(uint4*)&Vtb[gbase + (size_t)dl*1024 + n0 + c*8] = vv;
    }
  } else {
    bf16* dst = (t == 0) ? Qp : Kp;
    const int rg0 = row0 + wm;               // 64-row block, one bp
    const int bp  = rg0 >> 10;
    const int nb  = rg0 & 1023;
    const size_t gbase = (size_t)(bp*12 + h) * 65536;   // [bh][1024][64]
    #pragma unroll
    for (int dr = 0; dr < 8; dr++) {
      const int rl = dr*8 + (l >> 3);
      const int c  = l & 7;
      uint4 vv = *(const uint4*)&Ts[rl*72 + ((c ^ (rl & 7)) << 3)];
      *(uint4*)&dst[gbase + (size_t)(nb + rl)*64 + c*8] = vv;
    }
  }
}

// ---------------------------------------------------------------------------
// MFMA flash attention. (verified round-12 structure, unchanged)
// 512-thread blocks (8 waves), q-tile 128; 2-phase double-buffered K/V with
// counted vmcnt(2); swapped QK^T; log2-domain softmax; ones-MFMA denom;
// kt loop unrolled x2 (cur compile-time).
// ---------------------------------------------------------------------------
__global__ __launch_bounds__(512) void attn_mfma(
    const bf16* __restrict__ Qp, const bf16* __restrict__ Kp,
    const bf16* __restrict__ Vtb, bf16* __restrict__ ao)
{
  __shared__ __align__(16) bf16 QPs[128*64];    // Qs (prologue) then Ps
  __shared__ __align__(16) bf16 Ks[2][64*64];   // double-buffered K
  __shared__ __align__(16) bf16 Vs[2][64*64];   // double-buffered V^T
  bf16* Qs = QPs;
  bf16* Ps = QPs;
  const int tid = threadIdx.x;
  const int l   = tid & 63;
  const int w   = tid >> 6;                  // 0..7

  const int nwg = gridDim.x * gridDim.y;
  const int bid = blockIdx.y * gridDim.x + blockIdx.x;
  const int lb  = xcd_swizzle(bid, nwg);     // bh-major logical order
  const int qt  = lb & 7;                    // 0..7 (128-row q tiles)
  const int bh  = lb >> 3;                   // b*12 + h
  const size_t base = (size_t)bh * 65536;

  const int srow = w*8 + (l >> 3);           // 0..63 across 8 waves
  const int sch  = (l & 7) ^ (l >> 3);
  const bf16* Qst = Qp  + base + (size_t)(qt*128 + srow)*64 + sch*8;
  const bf16* Kst = Kp  + base + (size_t)srow*64   + sch*8;
  const bf16* Vst = Vtb + base + (size_t)srow*1024 + sch*8;

  // stage K/V tile tt into buffer b: ONE K DMA + ONE V DMA per wave
  #define STAGE_KV(tt, b)                                                    \
    { gload16(Kst + (size_t)(tt)*64*64, Ks[b] + (w*8)*64);                   \
      gload16(Vst + (size_t)(tt)*64,    Vs[b] + (w*8)*64); }

  // prologue: Q (2 DMAs/wave, 128 rows) + tile0 -> full drain, read Q frags,
  // stage tile1
  #pragma unroll
  for (int i = 0; i < 2; i++)
    gload16(Qst + (size_t)i*64*64, Qs + (i*64 + w*8)*64);
  STAGE_KV(0, 0);
  __syncthreads();                           // drains vmcnt -> Q + tile0 ready

  bf16x8 af[2];
  {
    const int row = w*16 + (l & 15);         // 0..127
    #pragma unroll
    for (int s = 0; s < 2; s++) {
      const int ch = (s*4 + (l >> 4)) ^ (row & 7);
      af[s] = *(const bf16x8*)&Qs[row*64 + ch*8];
    }
  }
  STAGE_KV(1, 1);                            // tile1 in flight (2 DMAs)

  bf16x8 ones;
  #pragma unroll
  for (int i = 0; i < 8; i++) ones[i] = (__bf16)1.0f;

  float m_i = -3.0e38f;                      // per-lane, q = w*16 + (l&15)
  f32x4 l_acc = {};                          // denominators, o layout
  f32x4 o[4] = {};                           // q-local=(l>>4)*4+v, d=ntd*16+(l&15)

  const int g    = l >> 4;                   // lane quarter
  const int qrow = w*16 + (l & 15);          // this lane's q-row (local)

  #pragma unroll 2
  for (int kt = 0; kt < 16; kt++) {
    const int cur = kt & 1;
    if (kt > 0) {
      // tile kt's 2 DMAs done (kt+1's 2 stay in flight); then all-wave sync
      if (kt < 15) { asm volatile("s_waitcnt vmcnt(2)" ::: "memory"); }
      else         { asm volatile("s_waitcnt vmcnt(0)" ::: "memory"); }
      __builtin_amdgcn_s_barrier();
      asm volatile("" ::: "memory");
    }
    const bf16* Ksb = Ks[cur];
    const bf16* Vsb = Vs[cur];

    // ---- S^T = K . Q^T : s[nt][v] = S[k = nt*16 + 4g + v][q = qrow] ----
    f32x4 s[4];
    __builtin_amdgcn_s_setprio(1);
    #pragma unroll
    for (int nt = 0; nt < 4; nt++) {
      f32x4 a = {};
      const int nrow = nt*16 + (l & 15);
      #pragma unroll
      for (int ss = 0; ss < 2; ss++) {
        const int ch = (ss*4 + (l >> 4)) ^ (nrow & 7);
        bf16x8 bg = *(const bf16x8*)&Ksb[nrow*64 + ch*8];
        a = __builtin_amdgcn_mfma_f32_16x16x32_bf16(bg, af[ss], a, 0, 0, 0);
      }
      s[nt] = a;
    }
    __builtin_amdgcn_s_setprio(0);

    // ---- online softmax (log2 domain), per-lane q-row ----
    float a0 = fmaxf(fmaxf(s[0][0], s[0][1]), s[0][2]);
    float a1 = fmaxf(fmaxf(s[0][3], s[1][0]), s[1][1]);
    float a2 = fmaxf(fmaxf(s[1][2], s[1][3]), s[2][0]);
    float a3 = fmaxf(fmaxf(s[2][1], s[2][2]), s[2][3]);
    float a4 = fmaxf(fmaxf(s[3][0], s[3][1]), s[3][2]);
    float b0 = fmaxf(fmaxf(a0, a1), a2);
    float b1 = fmaxf(fmaxf(a3, a4), s[3][3]);
    float mloc = fmaxf(b0, b1);
    mloc = fmaxf(mloc, __shfl_xor(mloc, 16));
    const float m0 = fmaxf(mloc, __shfl_xor(mloc, 32));

    if (!__all(m0 - m_i <= 8.0f)) {          // rescale (rare after tile 0)
      const float mx = fmaxf(m_i, m0);
      const float alpha = exp2f(m_i - mx);
      m_i = mx;
      float a_o[4];
      #pragma unroll
      for (int v = 0; v < 4; v++)            // alpha for o's q-local = 4g+v
        a_o[v] = __shfl(alpha, (l & 48) | ((g << 2) + v));
      #pragma unroll
      for (int v = 0; v < 4; v++) {
        l_acc[v] *= a_o[v];
        #pragma unroll
        for (int nt = 0; nt < 4; nt++) o[nt][v] *= a_o[v];
      }
    }

    // ---- P = 2^(S - m), pack to bf16, b64 store into Ps (wave-private) ----
    #pragma unroll
    for (int nt = 0; nt < 4; nt++) {
      const float p0 = exp2f(s[nt][0] - m_i);
      const float p1 = exp2f(s[nt][1] - m_i);
      const float p2 = exp2f(s[nt][2] - m_i);
      const float p3 = exp2f(s[nt][3] - m_i);
      const int k0 = nt*16 + (g << 2);       // 4 consecutive k
      const int ch = (k0 >> 3) ^ (qrow & 7);
      uint2 uu;
      uu.x = pk2(p0, p1);
      uu.y = pk2(p2, p3);
      *(uint2*)&Ps[qrow*64 + ch*8 + (k0 & 7)] = uu;
    }

    // ---- PV + l: o[q][d] += P[q][k] V^T[d][k]; l_acc += P . 1 ----
    __builtin_amdgcn_s_setprio(1);
    #pragma unroll
    for (int ss = 0; ss < 2; ss++) {
      const int pch  = (ss*4 + g) ^ (qrow & 7);
      bf16x8 pa = *(const bf16x8*)&Ps[qrow*64 + pch*8];
      l_acc = __builtin_amdgcn_mfma_f32_16x16x32_bf16(pa, ones, l_acc, 0,0,0);
      #pragma unroll
      for (int ntd = 0; ntd < 4; ntd++) {
        const int drow = ntd*16 + (l & 15);
        const int vch  = (ss*4 + (l >> 4)) ^ (drow & 7);
        bf16x8 vb = *(const bf16x8*)&Vsb[drow*64 + vch*8];
        o[ntd] = __builtin_amdgcn_mfma_f32_16x16x32_bf16(pa, vb, o[ntd], 0,0,0);
      }
    }
    __builtin_amdgcn_s_setprio(0);

    // all waves done reading buf[cur] -> safe to overwrite it with kt+2
    asm volatile("" ::: "memory");
    __builtin_amdgcn_s_barrier();
    asm volatile("" ::: "memory");
    if (kt + 2 < 16) STAGE_KV(kt + 2, cur);
  }
  #undef STAGE_KV

  // ---- epilogue: 1/l in-place (o layout), re-tile through Ps (wave-
  //      private rows), 16B coalesced stores ----
  const int b = bh / 12, h = bh - b*12;
  #pragma unroll
  for (int v = 0; v < 4; v++) {
    const float invv = 1.0f / l_acc[v];
    const int rl = g*4 + v;                  // 0..15 local row
    #pragma unroll
    for (int ntd = 0; ntd < 4; ntd++) {
      const int cl = ntd*16 + (l & 15);      // 0..63 local col
      Ps[(w*16 + rl)*64 + (((cl >> 3) ^ (rl & 7)) << 3) + (cl & 7)] =
          __float2bfloat16(o[ntd][v] * invv);
    }
  }
  #pragma unroll
  for (int e = 0; e < 2; e++) {
    const int rl = e*8 + (l >> 3);
    const int c  = l & 7;
    uint4 vv = *(const uint4*)&Ps[(w*16 + rl)*64 + ((c ^ (rl & 7)) << 3)];
    const int r = qt*128 + w*16 + rl;
    *(uint4*)&ao[((size_t)(b*1024 + r)) * 768 + h*64 + c*8] = vv;
  }
}

// ---------------------------------------------------------------------------
// Plain MFMA NT-GEMM + bias (proj). global_load_lds staging + XCD swizzle.
// ---------------------------------------------------------------------------
__global__ __launch_bounds__(256) void gemm_mfma(
    const bf16* __restrict__ Ab, const bf16* __restrict__ WT,
    const void* __restrict__ bias, void* __restrict__ Cout,
    const int Nd, const int K, const int c_row_off,
    const int* __restrict__ flag, const int bias_mode, const int c_mode)
{
  const int fl = *flag;
  const bool bbf = (bias_mode == 2) ? (fl != 0) : (bias_mode != 0);
  const bool cbf = (c_mode == 2) ? (fl != 0) : (c_mode != 0);

  __shared__ __align__(16) unsigned short As[128*64];
  __shared__ __align__(16) unsigned short Bs[128*64];

  const int tid = threadIdx.x;
  const int l   = tid & 63;
  const int w   = tid >> 6;
  const int wm  = (w & 1) * 64;
  const int wn  = (w >> 1) * 64;

  const int nwg = gridDim.x * gridDim.y;
  const int bid = blockIdx.y * gridDim.x + blockIdx.x;
  const int lb  = xcd_swizzle(bid, nwg);
  const int gy  = gridDim.y;
  const int brow = lb / gy;
  const int bcol = lb - brow * gy;
  const int row0 = brow * 128;
  const int col0 = bcol * 128;

  const int srow = w*8 + (l >> 3);
  const int sch  = (l & 7) ^ (l >> 3);
  const bf16* Ast = Ab + (size_t)(row0 + srow) * K + sch * 8;
  const bf16* Bst = WT + (size_t)(col0 + srow) * K + sch * 8;

  f32x4 acc[4][4] = {};

  for (int k0 = 0; k0 < K; k0 += 64) {
    __syncthreads();
    #pragma unroll
    for (int i = 0; i < 4; i++) {
      gload16(Ast + (size_t)i*32*K + k0, As + (i*32 + w*8)*64);
      gload16(Bst + (size_t)i*32*K + k0, Bs + (i*32 + w*8)*64);
    }
    __syncthreads();
    #pragma unroll
    for (int s = 0; s < 2; s++) {
      bf16x8 af[4], bg[4];
      const int ch = (s*4 + (l >> 4)) ^ (l & 7);
      #pragma unroll
      for (int i = 0; i < 4; i++) {
        const int rowm = wm + i*16 + (l & 15);
        const int rown = wn + i*16 + (l & 15);
        af[i] = *(const bf16x8*)&As[rowm*64 + ch*8];
        bg[i] = *(const bf16x8*)&Bs[rown*64 + ch*8];
      }
      #pragma unroll
      for (int i = 0; i < 4; i++)
        #pragma unroll
        for (int j = 0; j < 4; j++)
          acc[i][j] = __builtin_amdgcn_mfma_f32_16x16x32_bf16(
                          af[i], bg[j], acc[i][j], 0, 0, 0);
    }
  }

  const int cn    = col0 + wn + (l & 15);
  const int rbase = c_row_off + row0 + wm + (l >> 4) * 4;
  #pragma unroll
  for (int j = 0; j < 4; j++) {
    const int col = cn + j*16;
    const float bval = bbf ? tof(((const bf16*)bias)[col])
                           : ((const float*)bias)[col];
    #pragma unroll
    for (int i = 0; i < 4; i++) {
      #pragma unroll
      for (int v = 0; v < 4; v++) {
        const size_t r = (size_t)(rbase + i*16 + v);
        const float val = acc[i][j][v] + bval;
        if (cbf) ((bf16*)Cout)[r * Nd + col] = __float2bfloat16(val);
        else     ((float*)Cout)[r * Nd + col] = val;
      }
    }
  }
}

// ---------------------------------------------------------------------------
// ws: flag(256B) | WqkvT 3.54MB | WprojT 1.18MB |
//     xb/ao (ALIASED: xb dead after qkv, ao born in attn) | Qp | Kp | Vt
//     -> perb = 4 x 1.57MB/batch; CB=16 fits in ~105 MB workspace.
// ---------------------------------------------------------------------------
extern "C" void kernel_launch(void* const* d_in, const int* in_sizes, int n_in,
                              void* d_out, int out_size, void* d_ws, size_t ws_size,
                              hipStream_t stream)
{
  (void)in_sizes; (void)n_in; (void)out_size;
  const void* x     = d_in[0];
  const void* Wqkv  = d_in[1];
  const void* bqkv  = d_in[2];
  const void* Wproj = d_in[3];
  const void* bproj = d_in[4];
  const int*  pos_h = (const int*)d_in[5];
  const int*  pos_w = (const int*)d_in[6];

  int* flag = (int*)d_ws;
  char* p = (char*)d_ws + 256;
  bf16* WqkvT  = (bf16*)p; p += (size_t)QC_ * C_ * 2;
  bf16* WprojT = (bf16*)p; p += (size_t)C_ * C_ * 2;

  const size_t fixed = 256 + (size_t)QC_*C_*2 + (size_t)C_*C_*2;
  const size_t perb  = 4 * (size_t)N_ * C_ * 2;   // xb/ao, Qp, Kp, Vt per batch
  int CB = 16;
  if (ws_size < fixed + 16*perb) CB = 8;
  if (ws_size < fixed + 8*perb)  CB = 4;
  if (ws_size < fixed + 4*perb)  CB = 2;
  if (ws_size < fixed + 2*perb)  CB = 1;
  const int Mc = CB * N_;
  const size_t tsz = (size_t)Mc * C_;

  bf16* xb  = (bf16*)p;        // aliased with ao (disjoint lifetimes)
  bf16* Qp  = xb  + tsz;
  bf16* Kp  = Qp  + tsz;
  bf16* Vtb = Kp  + tsz;
  bf16* ao  = xb;              // xb dead after gemm_qkv_rope; stream-ordered

  detect_dtype<<<1, 256, 0, stream>>>((const unsigned*)x, flag);
  wt_cvt<<<dim3(QC_/32, C_/32), 256, 0, stream>>>(Wqkv, WqkvT, C_, QC_, flag);
  wt_cvt<<<dim3(C_/32,  C_/32), 256, 0, stream>>>(Wproj, WprojT, C_, C_, flag);

  for (int c0 = 0; c0 < B_; c0 += CB) {
    const int n4 = Mc * C_ / 4;
    cvt_x<<<(n4 + 255)/256, 256, 0, stream>>>(x, xb, flag, n4, c0 * N_ * C_ / 4);
    gemm_qkv_rope<<<dim3(Mc/128, QC_/128), 256, 0, stream>>>(
        xb, WqkvT, bqkv, Qp, Kp, Vtb, flag,
        pos_h + (size_t)c0*N_, pos_w + (size_t)c0*N_);
    attn_mfma<<<dim3(N_/128, CB*H_), 512, 0, stream>>>(Qp, Kp, Vtb, ao);
    gemm_mfma<<<dim3(Mc/128, C_/128), 256, 0, stream>>>(
        ao, WprojT, bproj, d_out, C_, C_, c0*N_, flag, 2, 2);
  }
}